// Round 3
// baseline (1907.279 us; speedup 1.0000x reference)
//
#include <hip/hip_runtime.h>
#include <hip/hip_bf16.h>

#define NU     50000
#define NEN    100000
#define NEDGE  2000000
#define NINTER 1000000
#define CH     64
#define NRELM1 9

// ---- init: f32 inputs -> f32 working buffers ----
__global__ __launch_bounds__(256) void k_init(
    const float* __restrict__ ue, const float* __restrict__ ee,
    const float* __restrict__ re, const float* __restrict__ wq,
    float* __restrict__ Ef32, float* __restrict__ Eres, float* __restrict__ Ures,
    float* __restrict__ Rel, float* __restrict__ Wq)
{
    int i = blockIdx.x * 256 + threadIdx.x;
    if (i < NEN * CH) { float f = ee[i]; Ef32[i] = f; Eres[i] = f; }
    if (i < NU * CH)  { Ures[i] = ue[i]; }
    if (i < NRELM1 * CH) Rel[i] = re[i];
    if (i < CH * CH)     Wq[i]  = wq[i];
}

// ---- Qe = Ef32 @ W  (W 64x64 in LDS; 4 rows/block) ----
__global__ __launch_bounds__(256) void k_gemm(
    const float* __restrict__ Ef32, const float* __restrict__ Wq, float* __restrict__ Qe)
{
    __shared__ float Wl[64 * 64];
    __shared__ float Rowl[4 * 64];
    int tid = threadIdx.x;
    for (int i = tid; i < 64 * 64; i += 256) Wl[i] = Wq[i];
    int row0 = blockIdx.x * 4;
    Rowl[tid] = Ef32[row0 * 64 + tid];
    __syncthreads();
    int rl = tid >> 6, c = tid & 63;
    float acc = 0.f;
#pragma unroll
    for (int k = 0; k < 64; ++k) acc += Rowl[rl * 64 + k] * Wl[k * 64 + c];
    Qe[(row0 + rl) * 64 + c] = acc;
}

// ---- zero accumulators ----
__global__ __launch_bounds__(256) void k_zero(
    float4* __restrict__ Eagg, float4* __restrict__ Uagg, float4* __restrict__ Den)
{
    const int nE = NEN * CH / 4;   // 1,600,000
    const int nU = NU * CH / 4;    //   800,000
    const int nD = NEN * 2 / 4;    //    50,000
    int i = blockIdx.x * 256 + threadIdx.x;
    float4 z = make_float4(0.f, 0.f, 0.f, 0.f);
    if (i < nE) Eagg[i] = z;
    else if (i < nE + nU) Uagg[i - nE] = z;
    else if (i < nE + nU + nD) Den[i - nE - nU] = z;
}

// ---- per-edge scores: 16 lanes/edge, float4 per lane ----
__global__ __launch_bounds__(256) void k_score(
    const int* __restrict__ eidx, const int* __restrict__ etype,
    const float* __restrict__ Qe, const float* __restrict__ Rel,
    float* __restrict__ Exps, float* __restrict__ Denom)
{
    int t = blockIdx.x * 256 + threadIdx.x;
    int e = t >> 4;
    if (e >= NEDGE) return;
    int lane = threadIdx.x & 15;
    int head = eidx[e];
    int tail = eidx[NEDGE + e];
    int rt   = etype[e] - 1;
    const float4 q = *(const float4*)(Qe + head * 64 + lane * 4);
    const float4 k = *(const float4*)(Qe + tail * 64 + lane * 4);
    const float4 r = *(const float4*)(Rel + rt * 64 + lane * 4);
    float p = q.x * k.x * r.x + q.y * k.y * r.y + q.z * k.z * r.z + q.w * k.w * r.w;
    // reduce within each 8-lane half (head 0: lanes 0-7, head 1: lanes 8-15)
    p += __shfl_xor(p, 1);
    p += __shfl_xor(p, 2);
    p += __shfl_xor(p, 4);
    float s  = p * 0.17677669529663687f;   // 1/sqrt(32)
    float ex = expf(s);                    // scores are tiny; max-subtraction unnecessary
    if ((lane & 7) == 0) {
        int h = lane >> 3;
        Exps[e * 2 + h] = ex;
        atomicAdd(&Denom[head * 2 + h], ex);
    }
}

// ---- weighted scatter into entity_agg: 64 lanes/edge ----
__global__ __launch_bounds__(256) void k_agg(
    const int* __restrict__ eidx, const int* __restrict__ etype,
    const float* __restrict__ Ef32, const float* __restrict__ Rel,
    const float* __restrict__ Exps, const float* __restrict__ Denom,
    float* __restrict__ Eagg)
{
    int t = blockIdx.x * 256 + threadIdx.x;
    int e = t >> 6;
    if (e >= NEDGE) return;
    int c = threadIdx.x & 63;
    int head = eidx[e];
    int tail = eidx[NEDGE + e];
    int rt   = etype[e] - 1;
    int h = c >> 5;
    float attn = Exps[e * 2 + h] / Denom[head * 2 + h];
    float v = Ef32[tail * 64 + c] * Rel[rt * 64 + c];
    atomicAdd(&Eagg[head * 64 + c], v * attn);
}

// ---- user aggregation: 64 lanes/inter-edge ----
__global__ __launch_bounds__(256) void k_inter(
    const int* __restrict__ ii, const float* __restrict__ iw,
    const float* __restrict__ Ef32, float* __restrict__ Uagg)
{
    int t = blockIdx.x * 256 + threadIdx.x;
    int i = t >> 6;
    if (i >= NINTER) return;
    int c = threadIdx.x & 63;
    int u   = ii[i];
    int ent = ii[NINTER + i];
    float w = iw[i];
    atomicAdd(&Uagg[u * 64 + c], w * Ef32[ent * 64 + c]);
}

// ---- l2-normalize rows + accumulate residual (1 wave per row) ----
__global__ __launch_bounds__(256) void k_norm(
    const float* __restrict__ agg, float* __restrict__ emb_out /*nullable*/,
    float* __restrict__ res, int nrows)
{
    int wave = threadIdx.x >> 6;
    int c    = threadIdx.x & 63;
    int row  = blockIdx.x * 4 + wave;
    if (row >= nrows) return;
    float v  = agg[row * 64 + c];
    float ss = v * v;
#pragma unroll
    for (int m = 1; m < 64; m <<= 1) ss += __shfl_xor(ss, m);
    float inv = 1.0f / fmaxf(sqrtf(ss), 1e-12f);
    float nv  = v * inv;
    if (emb_out) emb_out[row * 64 + c] = nv;
    res[row * 64 + c] += nv;
}

// ---- f32 residuals -> f32 output (entity then user, reference output dtype) ----
__global__ __launch_bounds__(256) void k_final(
    const float* __restrict__ Eres, const float* __restrict__ Ures,
    float* __restrict__ out)
{
    int i = blockIdx.x * 256 + threadIdx.x;
    if (i < NEN * CH) out[i] = Eres[i];
    else if (i < NEN * CH + NU * CH) out[i] = Ures[i - NEN * CH];
}

extern "C" void kernel_launch(void* const* d_in, const int* in_sizes, int n_in,
                              void* d_out, int out_size, void* d_ws, size_t ws_size,
                              hipStream_t stream)
{
    const float* ue = (const float*)d_in[0]; // user_emb    [50000,64] f32
    const float* ee = (const float*)d_in[1]; // entity_emb  [100000,64] f32
    const float* re = (const float*)d_in[2]; // relation    [9,64] f32
    const float* wq = (const float*)d_in[3]; // W_Q         [64,64] f32
    const float* iw = (const float*)d_in[4]; // inter_edge_w[1M] f32
    const int* eidx  = (const int*)d_in[5];  // edge_index  [2,2M]
    const int* etype = (const int*)d_in[6];  // edge_type   [2M]
    const int* ii    = (const int*)d_in[7];  // inter_edge  [2,1M]
    float* out = (float*)d_out;              // reference output dtype = float32

    // ws carve (f32), total ~145 MB
    float* Ef32  = (float*)d_ws;
    float* Qe    = Ef32  + (size_t)NEN * CH;
    float* Eagg  = Qe    + (size_t)NEN * CH;
    float* Eres  = Eagg  + (size_t)NEN * CH;
    float* Uagg  = Eres  + (size_t)NEN * CH;
    float* Ures  = Uagg  + (size_t)NU * CH;
    float* Exps  = Ures  + (size_t)NU * CH;
    float* Denom = Exps  + (size_t)NEDGE * 2;
    float* Rel   = Denom + (size_t)NEN * 2;
    float* Wq    = Rel   + (size_t)NRELM1 * CH;

    k_init<<<(NEN * CH) / 256, 256, 0, stream>>>(ue, ee, re, wq, Ef32, Eres, Ures, Rel, Wq);

    const int nZero = NEN * CH / 4 + NU * CH / 4 + NEN * 2 / 4; // 2,450,000
    for (int hop = 0; hop < 2; ++hop) {
        k_gemm <<<NEN / 4, 256, 0, stream>>>(Ef32, Wq, Qe);
        k_zero <<<(nZero + 255) / 256, 256, 0, stream>>>((float4*)Eagg, (float4*)Uagg, (float4*)Denom);
        k_score<<<NEDGE / 16, 256, 0, stream>>>(eidx, etype, Qe, Rel, Exps, Denom);
        k_agg  <<<NEDGE / 4, 256, 0, stream>>>(eidx, etype, Ef32, Rel, Exps, Denom, Eagg);
        k_inter<<<NINTER / 4, 256, 0, stream>>>(ii, iw, Ef32, Uagg);
        k_norm <<<NEN / 4, 256, 0, stream>>>(Eagg, Ef32, Eres, NEN);
        k_norm <<<NU / 4, 256, 0, stream>>>(Uagg, nullptr, Ures, NU);
    }
    k_final<<<(NEN * CH + NU * CH) / 256, 256, 0, stream>>>(Eres, Ures, out);
}

// Round 4
// 1464.743 us; speedup vs baseline: 1.3021x; 1.3021x over previous
//
#include <hip/hip_runtime.h>
#include <hip/hip_bf16.h>

#define NU     50000
#define NEN    100000
#define NEDGE  2000000
#define NINTER 1000000
#define CH     64
#define NRELM1 9

// ---- init: copy inputs to f32 work buffers, zero CSR counters ----
__global__ __launch_bounds__(256) void k_init(
    const float* __restrict__ ue, const float* __restrict__ ee,
    const float* __restrict__ re, const float* __restrict__ wq,
    float* __restrict__ Ecur, float* __restrict__ Eres, float* __restrict__ Ures,
    float* __restrict__ Rel, float* __restrict__ Wq,
    int* __restrict__ cntE, int* __restrict__ cntU)
{
    int i = blockIdx.x * 256 + threadIdx.x;           // grid covers NEN*CH
    if (i < NEN * CH) { float f = ee[i]; Ecur[i] = f; Eres[i] = f; }
    if (i < NU * CH)  { Ures[i] = ue[i]; }
    if (i < NRELM1 * CH) Rel[i] = re[i];
    if (i < CH * CH)     Wq[i]  = wq[i];
    if (i < NEN) cntE[i] = 0;
    if (i < NU)  cntU[i] = 0;
}

// ---- degree histograms (counters are L2-resident, atomics cheap) ----
__global__ __launch_bounds__(256) void k_hist(
    const int* __restrict__ eidx, const int* __restrict__ ii,
    int* __restrict__ cntE, int* __restrict__ cntU)
{
    int t = blockIdx.x * 256 + threadIdx.x;
    if (t < NEDGE) atomicAdd(&cntE[eidx[t]], 1);
    if (t < NINTER) atomicAdd(&cntU[ii[t]], 1);
}

// ---- prefix scan: block 0 -> entities, block 1 -> users ----
__global__ __launch_bounds__(1024) void k_scan(
    const int* __restrict__ cntE, int* __restrict__ startE, int* __restrict__ curE,
    const int* __restrict__ cntU, int* __restrict__ startU, int* __restrict__ curU)
{
    __shared__ int sh[1024];
    const int* cnt; int* start; int* cur; int n;
    if (blockIdx.x == 0) { cnt = cntE; start = startE; cur = curE; n = NEN; }
    else                 { cnt = cntU; start = startU; cur = curU; n = NU; }
    int t = threadIdx.x;
    int chunk = (n + 1023) >> 10;
    int lo = t * chunk, hi = min(lo + chunk, n);
    int sum = 0;
    for (int i = lo; i < hi; ++i) sum += cnt[i];
    sh[t] = sum; __syncthreads();
    for (int off = 1; off < 1024; off <<= 1) {
        int v = sh[t];
        if (t >= off) v += sh[t - off];
        __syncthreads(); sh[t] = v; __syncthreads();
    }
    int incl = sh[t];
    int run = incl - sum;                       // exclusive prefix
    for (int i = lo; i < hi; ++i) { start[i] = run; cur[i] = run; run += cnt[i]; }
    if (t == 1023) start[n] = incl;             // total
}

// ---- scatter edges into CSR slots ----
__global__ __launch_bounds__(256) void k_scatter(
    const int* __restrict__ eidx, const int* __restrict__ etype,
    const int* __restrict__ ii, const float* __restrict__ iw,
    int* __restrict__ curE, int* __restrict__ csrE,
    int* __restrict__ curU, int* __restrict__ csrU, float* __restrict__ wU)
{
    int t = blockIdx.x * 256 + threadIdx.x;
    if (t < NEDGE) {
        int head = eidx[t], tail = eidx[NEDGE + t], rt = etype[t] - 1;
        int pos = atomicAdd(&curE[head], 1);
        csrE[pos] = tail | (rt << 17);          // tail < 2^17, rt < 2^4
    }
    if (t < NINTER) {
        int u = ii[t], ent = ii[NINTER + t];
        int pos = atomicAdd(&curU[u], 1);
        csrU[pos] = ent;
        wU[pos] = iw[t];
    }
}

// ---- Qe = Ecur @ W  (W 64x64 in LDS; 4 rows/block) ----
__global__ __launch_bounds__(256) void k_gemm(
    const float* __restrict__ Ecur, const float* __restrict__ Wq, float* __restrict__ Qe)
{
    __shared__ float Wl[64 * 64];
    __shared__ float Rowl[4 * 64];
    int tid = threadIdx.x;
    for (int i = tid; i < 64 * 64; i += 256) Wl[i] = Wq[i];
    int row0 = blockIdx.x * 4;
    Rowl[tid] = Ecur[row0 * 64 + tid];
    __syncthreads();
    int rl = tid >> 6, c = tid & 63;
    float acc = 0.f;
#pragma unroll
    for (int k = 0; k < 64; ++k) acc += Rowl[rl * 64 + k] * Wl[k * 64 + c];
    Qe[(row0 + rl) * 64 + c] = acc;
}

// ---- per-entity fused attention: score+softmax(deferred-div)+agg+l2norm+residual ----
// one wave per node; lane = channel
__global__ __launch_bounds__(256) void k_node(
    const int* __restrict__ startE, const int* __restrict__ csrE,
    const float* __restrict__ Qe, const float* __restrict__ Ecur,
    const float* __restrict__ Rel,
    float* __restrict__ Enext, float* __restrict__ Eres)
{
    int row = blockIdx.x * 4 + (threadIdx.x >> 6);
    int c   = threadIdx.x & 63;
    int beg = startE[row], end = startE[row + 1];
    float q = Qe[row * 64 + c];
    float acc = 0.f, den = 0.f;
    for (int j = beg; j < end; ++j) {
        int p    = csrE[j];                   // wave-uniform -> broadcast
        int tail = p & 0x1FFFF;
        int rt   = p >> 17;
        float kt = Qe[tail * 64 + c];
        float te = Ecur[tail * 64 + c];
        float rl = Rel[rt * 64 + c];
        float sc = q * kt * rl;
        sc += __shfl_xor(sc, 1);              // reduce within 32-lane half (= head)
        sc += __shfl_xor(sc, 2);
        sc += __shfl_xor(sc, 4);
        sc += __shfl_xor(sc, 8);
        sc += __shfl_xor(sc, 16);
        float ex = expf(sc * 0.17677669529663687f);   // 1/sqrt(32); scores tiny, no max-sub needed
        den += ex;
        acc += ex * te * rl;
    }
    float val = (den > 0.f) ? acc / den : 0.f;
    float ss = val * val;                      // l2norm over the full 64-ch row
#pragma unroll
    for (int m = 1; m < 64; m <<= 1) ss += __shfl_xor(ss, m);
    float nv = val / fmaxf(sqrtf(ss), 1e-12f);
    Enext[row * 64 + c] = nv;
    Eres[row * 64 + c] += nv;
}

// ---- per-user fused aggregation + l2norm + residual ----
__global__ __launch_bounds__(256) void k_unode(
    const int* __restrict__ startU, const int* __restrict__ csrU,
    const float* __restrict__ wU, const float* __restrict__ Ecur,
    float* __restrict__ Ures)
{
    int row = blockIdx.x * 4 + (threadIdx.x >> 6);
    int c   = threadIdx.x & 63;
    int beg = startU[row], end = startU[row + 1];
    float acc = 0.f;
    for (int j = beg; j < end; ++j) {
        int ent = csrU[j];
        float w = wU[j];
        acc += w * Ecur[ent * 64 + c];
    }
    float ss = acc * acc;
#pragma unroll
    for (int m = 1; m < 64; m <<= 1) ss += __shfl_xor(ss, m);
    float nv = acc / fmaxf(sqrtf(ss), 1e-12f);
    Ures[row * 64 + c] += nv;
}

// ---- residuals -> f32 output ----
__global__ __launch_bounds__(256) void k_final(
    const float* __restrict__ Eres, const float* __restrict__ Ures,
    float* __restrict__ out)
{
    int i = blockIdx.x * 256 + threadIdx.x;
    if (i < NEN * CH) out[i] = Eres[i];
    else if (i < NEN * CH + NU * CH) out[i] = Ures[i - NEN * CH];
}

extern "C" void kernel_launch(void* const* d_in, const int* in_sizes, int n_in,
                              void* d_out, int out_size, void* d_ws, size_t ws_size,
                              hipStream_t stream)
{
    const float* ue = (const float*)d_in[0];
    const float* ee = (const float*)d_in[1];
    const float* re = (const float*)d_in[2];
    const float* wq = (const float*)d_in[3];
    const float* iw = (const float*)d_in[4];
    const int* eidx  = (const int*)d_in[5];
    const int* etype = (const int*)d_in[6];
    const int* ii    = (const int*)d_in[7];
    float* out = (float*)d_out;

    // ws carve (~133 MB)
    float* EbufA  = (float*)d_ws;                       // 6.4M
    float* EbufB  = EbufA  + (size_t)NEN * CH;          // 6.4M
    float* Qe     = EbufB  + (size_t)NEN * CH;          // 6.4M
    float* Eres   = Qe     + (size_t)NEN * CH;          // 6.4M
    float* Ures   = Eres   + (size_t)NEN * CH;          // 3.2M
    float* Rel    = Ures   + (size_t)NU * CH;
    float* Wq     = Rel    + (size_t)NRELM1 * CH;
    float* wU     = Wq     + (size_t)CH * CH;           // 1M
    int*   cntE   = (int*)(wU + (size_t)NINTER);
    int*   startE = cntE   + NEN;                       // NEN+1
    int*   curE   = startE + NEN + 1;
    int*   cntU   = curE   + NEN;
    int*   startU = cntU   + NU;                        // NU+1
    int*   curU   = startU + NU + 1;
    int*   csrE   = curU   + NU;                        // 2M
    int*   csrU   = csrE   + NEDGE;                     // 1M

    k_init<<<(NEN * CH) / 256, 256, 0, stream>>>(ue, ee, re, wq, EbufA, Eres, Ures,
                                                 Rel, Wq, cntE, cntU);
    k_hist<<<(NEDGE + 255) / 256, 256, 0, stream>>>(eidx, ii, cntE, cntU);
    k_scan<<<2, 1024, 0, stream>>>(cntE, startE, curE, cntU, startU, curU);
    k_scatter<<<(NEDGE + 255) / 256, 256, 0, stream>>>(eidx, etype, ii, iw,
                                                       curE, csrE, curU, csrU, wU);

    float* Ecur = EbufA;
    float* Enext = EbufB;
    for (int hop = 0; hop < 2; ++hop) {
        k_gemm <<<NEN / 4, 256, 0, stream>>>(Ecur, Wq, Qe);
        k_node <<<NEN / 4, 256, 0, stream>>>(startE, csrE, Qe, Ecur, Rel, Enext, Eres);
        k_unode<<<NU / 4, 256, 0, stream>>>(startU, csrU, wU, Ecur, Ures);
        float* tmp = Ecur; Ecur = Enext; Enext = tmp;
    }
    k_final<<<(NEN * CH + NU * CH) / 256, 256, 0, stream>>>(Eres, Ures, out);
}

// Round 5
// 1136.061 us; speedup vs baseline: 1.6789x; 1.2893x over previous
//
#include <hip/hip_runtime.h>

#define NU     50000
#define NEN    100000
#define NEDGE  2000000
#define NINTER 1000000
#define CH     64
#define NRELM1 9

// EQ layout: per entity, 128 floats: [0..63] = Qe row, [64..127] = Ecur row.

// ---- init: inputs -> work buffers (Eres/Ures live in d_out), zero counters ----
__global__ __launch_bounds__(256) void k_init(
    const float* __restrict__ ue, const float* __restrict__ ee,
    const float* __restrict__ re, const float* __restrict__ wq,
    float* __restrict__ EQ, float* __restrict__ Eres, float* __restrict__ Ures,
    float* __restrict__ Rel, float* __restrict__ Wq,
    int* __restrict__ cntE, int* __restrict__ cntU)
{
    int i = blockIdx.x * 256 + threadIdx.x;           // grid covers NEN*CH
    if (i < NEN * CH) {
        float f = ee[i];
        EQ[(i >> 6) * 128 + 64 + (i & 63)] = f;
        Eres[i] = f;
    }
    if (i < NU * CH)  Ures[i] = ue[i];
    if (i < NRELM1 * CH) Rel[i] = re[i];
    if (i < CH * CH)     Wq[i]  = wq[i];
    if (i < NEN) cntE[i] = 0;
    if (i < NU)  cntU[i] = 0;
}

// ---- degree histograms ----
__global__ __launch_bounds__(256) void k_hist(
    const int* __restrict__ eidx, const int* __restrict__ ii,
    int* __restrict__ cntE, int* __restrict__ cntU)
{
    int t = blockIdx.x * 256 + threadIdx.x;
    if (t < NEDGE) atomicAdd(&cntE[eidx[t]], 1);
    if (t < NINTER) atomicAdd(&cntU[ii[t]], 1);
}

// ---- prefix scan: block 0 -> entities, block 1 -> users ----
__global__ __launch_bounds__(1024) void k_scan(
    const int* __restrict__ cntE, int* __restrict__ startE, int* __restrict__ curE,
    const int* __restrict__ cntU, int* __restrict__ startU, int* __restrict__ curU)
{
    __shared__ int sh[1024];
    const int* cnt; int* start; int* cur; int n;
    if (blockIdx.x == 0) { cnt = cntE; start = startE; cur = curE; n = NEN; }
    else                 { cnt = cntU; start = startU; cur = curU; n = NU; }
    int t = threadIdx.x;
    int chunk = (n + 1023) >> 10;
    int lo = t * chunk, hi = min(lo + chunk, n);
    int sum = 0;
    for (int i = lo; i < hi; ++i) sum += cnt[i];
    sh[t] = sum; __syncthreads();
    for (int off = 1; off < 1024; off <<= 1) {
        int v = sh[t];
        if (t >= off) v += sh[t - off];
        __syncthreads(); sh[t] = v; __syncthreads();
    }
    int incl = sh[t];
    int run = incl - sum;                       // exclusive prefix
    for (int i = lo; i < hi; ++i) { start[i] = run; cur[i] = run; run += cnt[i]; }
    if (t == 1023) start[n] = incl;
}

// ---- scatter edges into CSR slots (user CSR packed as (ent, w) pairs) ----
__global__ __launch_bounds__(256) void k_scatter(
    const int* __restrict__ eidx, const int* __restrict__ etype,
    const int* __restrict__ ii, const float* __restrict__ iw,
    int* __restrict__ curE, int* __restrict__ csrE,
    int* __restrict__ curU, int* __restrict__ csrU2)
{
    int t = blockIdx.x * 256 + threadIdx.x;
    if (t < NEDGE) {
        int head = eidx[t], tail = eidx[NEDGE + t], rt = etype[t] - 1;
        int pos = atomicAdd(&curE[head], 1);
        csrE[pos] = tail | (rt << 17);          // tail < 2^17, rt < 2^4
    }
    if (t < NINTER) {
        int u = ii[t], ent = ii[NINTER + t];
        int pos = atomicAdd(&curU[u], 1);
        csrU2[2 * pos]     = ent;
        csrU2[2 * pos + 1] = __float_as_int(iw[t]);
    }
}

// ---- Qe-half = Ecur-half @ W  (W in LDS; 4 rows/block) ----
__global__ __launch_bounds__(256) void k_gemm(
    float* __restrict__ EQ, const float* __restrict__ Wq)
{
    __shared__ float Wl[64 * 64];
    __shared__ float Rowl[4 * 64];
    int tid = threadIdx.x;
    for (int i = tid; i < 64 * 64; i += 256) Wl[i] = Wq[i];
    int row0 = blockIdx.x * 4;
    int rl = tid >> 6, c = tid & 63;
    Rowl[tid] = EQ[(row0 + rl) * 128 + 64 + c];
    __syncthreads();
    float acc = 0.f;
#pragma unroll
    for (int k = 0; k < 64; ++k) acc += Rowl[rl * 64 + k] * Wl[k * 64 + c];
    EQ[(row0 + rl) * 128 + c] = acc;
}

// ---- fused per-node pass: entities (attention) + users (weighted mean) ----
// one wave per node; 4 edge-slots x 16 lanes; float4 (4 channels) per lane
__global__ __launch_bounds__(256) void k_fused(
    const int* __restrict__ startE, const int* __restrict__ csrE,
    const float* __restrict__ EQ, const float* __restrict__ Rel,
    float* __restrict__ EQnext, float* __restrict__ Eres,
    const int* __restrict__ startU, const int* __restrict__ csrU2,
    float* __restrict__ Ures)
{
    int wid  = blockIdx.x * 4 + (threadIdx.x >> 6);
    int lane = threadIdx.x & 63;
    int g = lane & 15, s = lane >> 4;
    int c4 = g * 4;                             // this lane's channel group

    if (wid < NEN) {
        int row = wid;
        int beg = startE[row], end = startE[row + 1];
        float4 q = *(const float4*)(EQ + (size_t)row * 128 + c4);
        float4 acc = make_float4(0.f, 0.f, 0.f, 0.f);
        float den = 0.f;
        for (int j = beg; j < end; j += 4) {
            int jj = j + s;
            bool act = (jj < end);
            int p = csrE[act ? jj : beg];
            int tail = p & 0x1FFFF;
            int rt   = p >> 17;
            const float* base = EQ + (size_t)tail * 128 + c4;
            float4 kt  = *(const float4*)(base);        // Qe[tail]
            float4 te  = *(const float4*)(base + 64);   // Ecur[tail]
            float4 rl4 = *(const float4*)(Rel + rt * 64 + c4);
            float sc = q.x * kt.x * rl4.x + q.y * kt.y * rl4.y
                     + q.z * kt.z * rl4.z + q.w * kt.w * rl4.w;
            sc += __shfl_xor(sc, 1);       // reduce 8 lanes = one head, intra-slot
            sc += __shfl_xor(sc, 2);
            sc += __shfl_xor(sc, 4);
            float ex = __expf(sc * 0.17677669529663687f);  // 1/sqrt(32); scores tiny
            ex = act ? ex : 0.f;
            den += ex;
            acc.x += ex * te.x * rl4.x;
            acc.y += ex * te.y * rl4.y;
            acc.z += ex * te.z * rl4.z;
            acc.w += ex * te.w * rl4.w;
        }
        // cross-slot totals (each slot covered a disjoint edge subset)
        acc.x += __shfl_xor(acc.x, 16); acc.x += __shfl_xor(acc.x, 32);
        acc.y += __shfl_xor(acc.y, 16); acc.y += __shfl_xor(acc.y, 32);
        acc.z += __shfl_xor(acc.z, 16); acc.z += __shfl_xor(acc.z, 32);
        acc.w += __shfl_xor(acc.w, 16); acc.w += __shfl_xor(acc.w, 32);
        den   += __shfl_xor(den, 16);   den   += __shfl_xor(den, 32);
        float invd = (den > 0.f) ? 1.f / den : 0.f;   // deferred softmax division
        float4 val = make_float4(acc.x * invd, acc.y * invd, acc.z * invd, acc.w * invd);
        float ss = val.x * val.x + val.y * val.y + val.z * val.z + val.w * val.w;
        ss += __shfl_xor(ss, 1); ss += __shfl_xor(ss, 2);
        ss += __shfl_xor(ss, 4); ss += __shfl_xor(ss, 8);   // 16 g-lanes = all 64 ch
        float inv = 1.f / fmaxf(sqrtf(ss), 1e-12f);
        val.x *= inv; val.y *= inv; val.z *= inv; val.w *= inv;
        if (s == 0) {                       // one slot writes (all slots identical)
            *(float4*)(EQnext + (size_t)row * 128 + 64 + c4) = val;
            float4 r0 = *(const float4*)(Eres + (size_t)row * 64 + c4);
            r0.x += val.x; r0.y += val.y; r0.z += val.z; r0.w += val.w;
            *(float4*)(Eres + (size_t)row * 64 + c4) = r0;
        }
    } else {
        int row = wid - NEN;                // user node
        int beg = startU[row], end = startU[row + 1];
        float4 acc = make_float4(0.f, 0.f, 0.f, 0.f);
        for (int j = beg; j < end; j += 4) {
            int jj = j + s;
            bool act = (jj < end);
            int idx = act ? jj : beg;
            int2 ew = *(const int2*)(csrU2 + 2 * (size_t)idx);
            float w = act ? __int_as_float(ew.y) : 0.f;
            float4 te = *(const float4*)(EQ + (size_t)ew.x * 128 + 64 + c4);
            acc.x += w * te.x; acc.y += w * te.y; acc.z += w * te.z; acc.w += w * te.w;
        }
        acc.x += __shfl_xor(acc.x, 16); acc.x += __shfl_xor(acc.x, 32);
        acc.y += __shfl_xor(acc.y, 16); acc.y += __shfl_xor(acc.y, 32);
        acc.z += __shfl_xor(acc.z, 16); acc.z += __shfl_xor(acc.z, 32);
        acc.w += __shfl_xor(acc.w, 16); acc.w += __shfl_xor(acc.w, 32);
        float ss = acc.x * acc.x + acc.y * acc.y + acc.z * acc.z + acc.w * acc.w;
        ss += __shfl_xor(ss, 1); ss += __shfl_xor(ss, 2);
        ss += __shfl_xor(ss, 4); ss += __shfl_xor(ss, 8);
        float inv = 1.f / fmaxf(sqrtf(ss), 1e-12f);
        if (s == 0) {
            float4 r0 = *(const float4*)(Ures + (size_t)row * 64 + c4);
            r0.x += acc.x * inv; r0.y += acc.y * inv;
            r0.z += acc.z * inv; r0.w += acc.w * inv;
            *(float4*)(Ures + (size_t)row * 64 + c4) = r0;
        }
    }
}

extern "C" void kernel_launch(void* const* d_in, const int* in_sizes, int n_in,
                              void* d_out, int out_size, void* d_ws, size_t ws_size,
                              hipStream_t stream)
{
    const float* ue = (const float*)d_in[0];
    const float* ee = (const float*)d_in[1];
    const float* re = (const float*)d_in[2];
    const float* wq = (const float*)d_in[3];
    const float* iw = (const float*)d_in[4];
    const int* eidx  = (const int*)d_in[5];
    const int* etype = (const int*)d_in[6];
    const int* ii    = (const int*)d_in[7];

    float* Eres = (float*)d_out;                 // residuals live in d_out directly
    float* Ures = Eres + (size_t)NEN * CH;

    // ws carve (~120 MB)
    float* EQ_A  = (float*)d_ws;                 // NEN*128
    float* EQ_B  = EQ_A + (size_t)NEN * 128;     // NEN*128
    float* Rel   = EQ_B + (size_t)NEN * 128;
    float* Wq    = Rel  + (size_t)NRELM1 * CH;
    int* cntE    = (int*)(Wq + (size_t)CH * CH);
    int* startE  = cntE   + NEN;                 // NEN+1
    int* curE    = startE + NEN + 1;
    int* cntU    = curE   + NEN;
    int* startU  = cntU   + NU;                  // NU+1
    int* curU    = startU + NU + 1;
    int* csrE    = curU   + NU;                  // NEDGE
    int* csrU2   = csrE   + NEDGE;               // 2*NINTER (8B-aligned: even offset)

    k_init<<<(NEN * CH) / 256, 256, 0, stream>>>(ue, ee, re, wq, EQ_A, Eres, Ures,
                                                 Rel, Wq, cntE, cntU);
    k_hist<<<(NEDGE + 255) / 256, 256, 0, stream>>>(eidx, ii, cntE, cntU);
    k_scan<<<2, 1024, 0, stream>>>(cntE, startE, curE, cntU, startU, curU);
    k_scatter<<<(NEDGE + 255) / 256, 256, 0, stream>>>(eidx, etype, ii, iw,
                                                       curE, csrE, curU, csrU2);

    float* EQc = EQ_A;
    float* EQn = EQ_B;
    for (int hop = 0; hop < 2; ++hop) {
        k_gemm <<<NEN / 4, 256, 0, stream>>>(EQc, Wq);
        k_fused<<<(NEN + NU) / 4, 256, 0, stream>>>(startE, csrE, EQc, Rel,
                                                    EQn, Eres, startU, csrU2, Ures);
        float* tmp = EQc; EQc = EQn; EQn = tmp;
    }
}

// Round 6
// 933.089 us; speedup vs baseline: 2.0440x; 1.2175x over previous
//
#include <hip/hip_runtime.h>

#define NU     50000
#define NEN    100000
#define NEDGE  2000000
#define NINTER 1000000
#define CH     64
#define NRELM1 9

// EQ layout: per entity, 128 floats: [0..63] = Qe row, [64..127] = Ecur row.

// ---- init: inputs -> work buffers (Eres/Ures live in d_out), zero counters ----
__global__ __launch_bounds__(256) void k_init(
    const float* __restrict__ ue, const float* __restrict__ ee,
    const float* __restrict__ re, const float* __restrict__ wq,
    float* __restrict__ EQ, float* __restrict__ Eres, float* __restrict__ Ures,
    float* __restrict__ Rel, float* __restrict__ Wq,
    int* __restrict__ cntE, int* __restrict__ cntU, int* __restrict__ cursors)
{
    int i = blockIdx.x * 256 + threadIdx.x;           // grid covers NEN*CH
    if (i < NEN * CH) {
        float f = ee[i];
        EQ[(i >> 6) * 128 + 64 + (i & 63)] = f;
        Eres[i] = f;
    }
    if (i < NU * CH)  Ures[i] = ue[i];
    if (i < NRELM1 * CH) Rel[i] = re[i];
    if (i < CH * CH)     Wq[i]  = wq[i];
    if (i < NEN) cntE[i] = 0;
    if (i < NU)  cntU[i] = 0;
    if (i < 2)   cursors[i] = 0;
}

// ---- degree histograms ----
__global__ __launch_bounds__(256) void k_hist(
    const int* __restrict__ eidx, const int* __restrict__ ii,
    int* __restrict__ cntE, int* __restrict__ cntU)
{
    int t = blockIdx.x * 256 + threadIdx.x;
    if (t < NEDGE) atomicAdd(&cntE[eidx[t]], 1);
    if (t < NINTER) atomicAdd(&cntU[ii[t]], 1);
}

// ---- CSR start allocation: unordered contiguous ranges via wave-aggregated atomics ----
__global__ __launch_bounds__(256) void k_alloc(
    const int* __restrict__ cntE, int* __restrict__ startE, int* __restrict__ curE,
    const int* __restrict__ cntU, int* __restrict__ startU, int* __restrict__ curU,
    int* __restrict__ cursors)
{
    const int nbE = (NEN + 255) >> 8;
    int b = blockIdx.x;
    const int* cnt; int* start; int* cur; int* cursor; int n; int node;
    if (b < nbE) { cnt = cntE; start = startE; cur = curE; cursor = cursors;     n = NEN;
                   node = b * 256 + threadIdx.x; }
    else         { cnt = cntU; start = startU; cur = curU; cursor = cursors + 1; n = NU;
                   node = (b - nbE) * 256 + threadIdx.x; }
    int c = (node < n) ? cnt[node] : 0;
    int lane = threadIdx.x & 63;
    int pre = c;                                // inclusive wave prefix sum
#pragma unroll
    for (int m = 1; m < 64; m <<= 1) {
        int v = __shfl_up(pre, m);
        if (lane >= m) pre += v;
    }
    int total = __shfl(pre, 63);
    int base = 0;
    if (lane == 63) base = atomicAdd(cursor, total);
    base = __shfl(base, 63);
    if (node < n) {
        int st = base + pre - c;                // exclusive within wave
        start[node] = st;
        cur[node]   = st;
    }
}

// ---- scatter edges into CSR slots (user CSR packed as (ent, w) pairs) ----
__global__ __launch_bounds__(256) void k_scatter(
    const int* __restrict__ eidx, const int* __restrict__ etype,
    const int* __restrict__ ii, const float* __restrict__ iw,
    int* __restrict__ curE, int* __restrict__ csrE,
    int* __restrict__ curU, int* __restrict__ csrU2)
{
    int t = blockIdx.x * 256 + threadIdx.x;
    if (t < NEDGE) {
        int head = eidx[t], tail = eidx[NEDGE + t], rt = etype[t] - 1;
        int pos = atomicAdd(&curE[head], 1);
        csrE[pos] = tail | (rt << 17);          // tail < 2^17, rt < 2^4
    }
    if (t < NINTER) {
        int u = ii[t], ent = ii[NINTER + t];
        int pos = atomicAdd(&curU[u], 1);
        csrU2[2 * pos]     = ent;
        csrU2[2 * pos + 1] = __float_as_int(iw[t]);
    }
}

// ---- Qe-half = Ecur-half @ W  (W in LDS; 4 rows/block) ----
__global__ __launch_bounds__(256) void k_gemm(
    float* __restrict__ EQ, const float* __restrict__ Wq)
{
    __shared__ float Wl[64 * 64];
    __shared__ float Rowl[4 * 64];
    int tid = threadIdx.x;
    for (int i = tid; i < 64 * 64; i += 256) Wl[i] = Wq[i];
    int row0 = blockIdx.x * 4;
    int rl = tid >> 6, c = tid & 63;
    Rowl[tid] = EQ[(row0 + rl) * 128 + 64 + c];
    __syncthreads();
    float acc = 0.f;
#pragma unroll
    for (int k = 0; k < 64; ++k) acc += Rowl[rl * 64 + k] * Wl[k * 64 + c];
    EQ[(row0 + rl) * 128 + c] = acc;
}

// ---- fused per-node pass: entities (attention) + users (weighted mean) ----
// one wave per node; 4 edge-slots x 16 lanes; float4 (4 channels) per lane
__global__ __launch_bounds__(256) void k_fused(
    const int* __restrict__ startE, const int* __restrict__ cntE,
    const int* __restrict__ csrE,
    const float* __restrict__ EQ, const float* __restrict__ Rel,
    float* __restrict__ EQnext, float* __restrict__ Eres,
    const int* __restrict__ startU, const int* __restrict__ cntU,
    const int* __restrict__ csrU2, float* __restrict__ Ures)
{
    int wid  = blockIdx.x * 4 + (threadIdx.x >> 6);
    int lane = threadIdx.x & 63;
    int g = lane & 15, s = lane >> 4;
    int c4 = g * 4;                             // this lane's channel group

    if (wid < NEN) {
        int row = wid;
        int beg = startE[row], end = beg + cntE[row];
        float4 q = *(const float4*)(EQ + (size_t)row * 128 + c4);
        float4 acc = make_float4(0.f, 0.f, 0.f, 0.f);
        float den = 0.f;
        for (int j = beg; j < end; j += 4) {
            int jj = j + s;
            bool act = (jj < end);
            int p = csrE[act ? jj : beg];
            int tail = p & 0x1FFFF;
            int rt   = p >> 17;
            const float* base = EQ + (size_t)tail * 128 + c4;
            float4 kt  = *(const float4*)(base);        // Qe[tail]
            float4 te  = *(const float4*)(base + 64);   // Ecur[tail]
            float4 rl4 = *(const float4*)(Rel + rt * 64 + c4);
            float sc = q.x * kt.x * rl4.x + q.y * kt.y * rl4.y
                     + q.z * kt.z * rl4.z + q.w * kt.w * rl4.w;
            sc += __shfl_xor(sc, 1);       // reduce 8 lanes = one head, intra-slot
            sc += __shfl_xor(sc, 2);
            sc += __shfl_xor(sc, 4);
            float ex = __expf(sc * 0.17677669529663687f);  // 1/sqrt(32); scores tiny
            ex = act ? ex : 0.f;
            den += ex;
            acc.x += ex * te.x * rl4.x;
            acc.y += ex * te.y * rl4.y;
            acc.z += ex * te.z * rl4.z;
            acc.w += ex * te.w * rl4.w;
        }
        // cross-slot totals (each slot covered a disjoint edge subset)
        acc.x += __shfl_xor(acc.x, 16); acc.x += __shfl_xor(acc.x, 32);
        acc.y += __shfl_xor(acc.y, 16); acc.y += __shfl_xor(acc.y, 32);
        acc.z += __shfl_xor(acc.z, 16); acc.z += __shfl_xor(acc.z, 32);
        acc.w += __shfl_xor(acc.w, 16); acc.w += __shfl_xor(acc.w, 32);
        den   += __shfl_xor(den, 16);   den   += __shfl_xor(den, 32);
        float invd = (den > 0.f) ? 1.f / den : 0.f;   // deferred softmax division
        float4 val = make_float4(acc.x * invd, acc.y * invd, acc.z * invd, acc.w * invd);
        float ss = val.x * val.x + val.y * val.y + val.z * val.z + val.w * val.w;
        ss += __shfl_xor(ss, 1); ss += __shfl_xor(ss, 2);
        ss += __shfl_xor(ss, 4); ss += __shfl_xor(ss, 8);   // 16 g-lanes = all 64 ch
        float inv = 1.f / fmaxf(sqrtf(ss), 1e-12f);
        val.x *= inv; val.y *= inv; val.z *= inv; val.w *= inv;
        if (s == 0) {                       // one slot writes (all slots identical)
            *(float4*)(EQnext + (size_t)row * 128 + 64 + c4) = val;
            float4 r0 = *(const float4*)(Eres + (size_t)row * 64 + c4);
            r0.x += val.x; r0.y += val.y; r0.z += val.z; r0.w += val.w;
            *(float4*)(Eres + (size_t)row * 64 + c4) = r0;
        }
    } else {
        int row = wid - NEN;                // user node
        int beg = startU[row], end = beg + cntU[row];
        float4 acc = make_float4(0.f, 0.f, 0.f, 0.f);
        for (int j = beg; j < end; j += 4) {
            int jj = j + s;
            bool act = (jj < end);
            int idx = act ? jj : beg;
            int2 ew = *(const int2*)(csrU2 + 2 * (size_t)idx);
            float w = act ? __int_as_float(ew.y) : 0.f;
            float4 te = *(const float4*)(EQ + (size_t)ew.x * 128 + 64 + c4);
            acc.x += w * te.x; acc.y += w * te.y; acc.z += w * te.z; acc.w += w * te.w;
        }
        acc.x += __shfl_xor(acc.x, 16); acc.x += __shfl_xor(acc.x, 32);
        acc.y += __shfl_xor(acc.y, 16); acc.y += __shfl_xor(acc.y, 32);
        acc.z += __shfl_xor(acc.z, 16); acc.z += __shfl_xor(acc.z, 32);
        acc.w += __shfl_xor(acc.w, 16); acc.w += __shfl_xor(acc.w, 32);
        float ss = acc.x * acc.x + acc.y * acc.y + acc.z * acc.z + acc.w * acc.w;
        ss += __shfl_xor(ss, 1); ss += __shfl_xor(ss, 2);
        ss += __shfl_xor(ss, 4); ss += __shfl_xor(ss, 8);
        float inv = 1.f / fmaxf(sqrtf(ss), 1e-12f);
        if (s == 0) {
            float4 r0 = *(const float4*)(Ures + (size_t)row * 64 + c4);
            r0.x += acc.x * inv; r0.y += acc.y * inv;
            r0.z += acc.z * inv; r0.w += acc.w * inv;
            *(float4*)(Ures + (size_t)row * 64 + c4) = r0;
        }
    }
}

extern "C" void kernel_launch(void* const* d_in, const int* in_sizes, int n_in,
                              void* d_out, int out_size, void* d_ws, size_t ws_size,
                              hipStream_t stream)
{
    const float* ue = (const float*)d_in[0];
    const float* ee = (const float*)d_in[1];
    const float* re = (const float*)d_in[2];
    const float* wq = (const float*)d_in[3];
    const float* iw = (const float*)d_in[4];
    const int* eidx  = (const int*)d_in[5];
    const int* etype = (const int*)d_in[6];
    const int* ii    = (const int*)d_in[7];

    float* Eres = (float*)d_out;                 // residuals live in d_out directly
    float* Ures = Eres + (size_t)NEN * CH;

    // ws carve (~131 MB)
    float* EQ_A  = (float*)d_ws;                 // NEN*128
    float* EQ_B  = EQ_A + (size_t)NEN * 128;     // NEN*128
    float* Rel   = EQ_B + (size_t)NEN * 128;
    float* Wq    = Rel  + (size_t)NRELM1 * CH;
    int* cntE    = (int*)(Wq + (size_t)CH * CH);
    int* startE  = cntE    + NEN;
    int* curE    = startE  + NEN;
    int* cntU    = curE    + NEN;
    int* startU  = cntU    + NU;
    int* curU    = startU  + NU;
    int* cursors = curU    + NU;                 // 2 ints
    int* csrE    = cursors + 2;                  // NEDGE (even offset -> 8B align ok)
    int* csrU2   = csrE    + NEDGE;              // 2*NINTER

    const int nbE = (NEN + 255) >> 8, nbU = (NU + 255) >> 8;

    k_init<<<(NEN * CH) / 256, 256, 0, stream>>>(ue, ee, re, wq, EQ_A, Eres, Ures,
                                                 Rel, Wq, cntE, cntU, cursors);
    k_hist<<<(NEDGE + 255) / 256, 256, 0, stream>>>(eidx, ii, cntE, cntU);
    k_alloc<<<nbE + nbU, 256, 0, stream>>>(cntE, startE, curE, cntU, startU, curU, cursors);
    k_scatter<<<(NEDGE + 255) / 256, 256, 0, stream>>>(eidx, etype, ii, iw,
                                                       curE, csrE, curU, csrU2);

    float* EQc = EQ_A;
    float* EQn = EQ_B;
    for (int hop = 0; hop < 2; ++hop) {
        k_gemm <<<NEN / 4, 256, 0, stream>>>(EQc, Wq);
        k_fused<<<(NEN + NU) / 4, 256, 0, stream>>>(startE, cntE, csrE, EQc, Rel,
                                                    EQn, Eres, startU, cntU, csrU2, Ures);
        float* tmp = EQc; EQc = EQn; EQn = tmp;
    }
}

// Round 7
// 900.725 us; speedup vs baseline: 2.1175x; 1.0359x over previous
//
#include <hip/hip_runtime.h>

#define NU     50000
#define NEN    100000
#define NEDGE  2000000
#define NINTER 1000000
#define CH     64
#define NRELM1 9

// EQ layout: per entity, 128 floats: [0..63] = Qe row, [64..127] = Ecur row.

// ---- init: inputs -> work buffers (Eres/Ures live in d_out), zero counters ----
__global__ __launch_bounds__(256) void k_init(
    const float* __restrict__ ue, const float* __restrict__ ee,
    const float* __restrict__ re, const float* __restrict__ wq,
    float* __restrict__ EQ, float* __restrict__ Eres, float* __restrict__ Ures,
    float* __restrict__ Rel, float* __restrict__ Wq,
    int* __restrict__ cntE, int* __restrict__ cntU, int* __restrict__ cursors)
{
    int i = blockIdx.x * 256 + threadIdx.x;           // grid covers NEN*CH
    if (i < NEN * CH) {
        float f = ee[i];
        EQ[(i >> 6) * 128 + 64 + (i & 63)] = f;
        Eres[i] = f;
    }
    if (i < NU * CH)  Ures[i] = ue[i];
    if (i < NRELM1 * CH) Rel[i] = re[i];
    if (i < CH * CH)     Wq[i]  = wq[i];
    if (i < NEN) cntE[i] = 0;
    if (i < NU)  cntU[i] = 0;
    if (i < 2)   cursors[i] = 0;
}

// ---- degree histograms ----
__global__ __launch_bounds__(256) void k_hist(
    const int* __restrict__ eidx, const int* __restrict__ ii,
    int* __restrict__ cntE, int* __restrict__ cntU)
{
    int t = blockIdx.x * 256 + threadIdx.x;
    if (t < NEDGE) atomicAdd(&cntE[eidx[t]], 1);
    if (t < NINTER) atomicAdd(&cntU[ii[t]], 1);
}

// ---- CSR start allocation: unordered contiguous ranges via wave-aggregated atomics ----
__global__ __launch_bounds__(256) void k_alloc(
    const int* __restrict__ cntE, int* __restrict__ startE, int* __restrict__ curE,
    const int* __restrict__ cntU, int* __restrict__ startU, int* __restrict__ curU,
    int* __restrict__ cursors)
{
    const int nbE = (NEN + 255) >> 8;
    int b = blockIdx.x;
    const int* cnt; int* start; int* cur; int* cursor; int n; int node;
    if (b < nbE) { cnt = cntE; start = startE; cur = curE; cursor = cursors;     n = NEN;
                   node = b * 256 + threadIdx.x; }
    else         { cnt = cntU; start = startU; cur = curU; cursor = cursors + 1; n = NU;
                   node = (b - nbE) * 256 + threadIdx.x; }
    int c = (node < n) ? cnt[node] : 0;
    int lane = threadIdx.x & 63;
    int pre = c;                                // inclusive wave prefix sum
#pragma unroll
    for (int m = 1; m < 64; m <<= 1) {
        int v = __shfl_up(pre, m);
        if (lane >= m) pre += v;
    }
    int total = __shfl(pre, 63);
    int base = 0;
    if (lane == 63) base = atomicAdd(cursor, total);
    base = __shfl(base, 63);
    if (node < n) {
        int st = base + pre - c;                // exclusive within wave
        start[node] = st;
        cur[node]   = st;
    }
}

// ---- scatter edges into CSR slots ----
// Stores go agent-scope (sc1) so partial 64B lines merge in the SHARED L3,
// not in per-XCD non-coherent L2s (which caused ~12x HBM write amplification).
__global__ __launch_bounds__(256) void k_scatter(
    const int* __restrict__ eidx, const int* __restrict__ etype,
    const int* __restrict__ ii, const float* __restrict__ iw,
    int* __restrict__ curE, int* __restrict__ csrE,
    int* __restrict__ curU, unsigned long long* __restrict__ csrU2)
{
    int t = blockIdx.x * 256 + threadIdx.x;
    if (t < NEDGE) {
        int head = eidx[t], tail = eidx[NEDGE + t], rt = etype[t] - 1;
        int pos = atomicAdd(&curE[head], 1);
        __hip_atomic_store(&csrE[pos], tail | (rt << 17),
                           __ATOMIC_RELAXED, __HIP_MEMORY_SCOPE_AGENT);
    }
    if (t < NINTER) {
        int u = ii[t], ent = ii[NINTER + t];
        int pos = atomicAdd(&curU[u], 1);
        unsigned long long rec = (unsigned long long)(unsigned)ent
                               | ((unsigned long long)__float_as_uint(iw[t]) << 32);
        __hip_atomic_store(&csrU2[pos], rec,
                           __ATOMIC_RELAXED, __HIP_MEMORY_SCOPE_AGENT);
    }
}

// ---- Qe-half = Ecur-half @ W  (W in LDS; 4 rows/block) ----
__global__ __launch_bounds__(256) void k_gemm(
    float* __restrict__ EQ, const float* __restrict__ Wq)
{
    __shared__ float Wl[64 * 64];
    __shared__ float Rowl[4 * 64];
    int tid = threadIdx.x;
    for (int i = tid; i < 64 * 64; i += 256) Wl[i] = Wq[i];
    int row0 = blockIdx.x * 4;
    int rl = tid >> 6, c = tid & 63;
    Rowl[tid] = EQ[(row0 + rl) * 128 + 64 + c];
    __syncthreads();
    float acc = 0.f;
#pragma unroll
    for (int k = 0; k < 64; ++k) acc += Rowl[rl * 64 + k] * Wl[k * 64 + c];
    EQ[(row0 + rl) * 128 + c] = acc;
}

// ---- fused per-node pass: entities (attention) + users (weighted mean) ----
// one wave per node; 4 edge-slots x 16 lanes; float4 (4 channels) per lane
__global__ __launch_bounds__(256) void k_fused(
    const int* __restrict__ startE, const int* __restrict__ cntE,
    const int* __restrict__ csrE,
    const float* __restrict__ EQ, const float* __restrict__ Rel,
    float* __restrict__ EQnext, float* __restrict__ Eres,
    const int* __restrict__ startU, const int* __restrict__ cntU,
    const int* __restrict__ csrU2, float* __restrict__ Ures)
{
    int wid  = blockIdx.x * 4 + (threadIdx.x >> 6);
    int lane = threadIdx.x & 63;
    int g = lane & 15, s = lane >> 4;
    int c4 = g * 4;                             // this lane's channel group

    if (wid < NEN) {
        int row = wid;
        int beg = startE[row], end = beg + cntE[row];
        float4 q = *(const float4*)(EQ + (size_t)row * 128 + c4);
        float4 acc = make_float4(0.f, 0.f, 0.f, 0.f);
        float den = 0.f;
        for (int j = beg; j < end; j += 4) {
            int jj = j + s;
            bool act = (jj < end);
            int p = csrE[act ? jj : beg];
            int tail = p & 0x1FFFF;
            int rt   = p >> 17;
            const float* base = EQ + (size_t)tail * 128 + c4;
            float4 kt  = *(const float4*)(base);        // Qe[tail]
            float4 te  = *(const float4*)(base + 64);   // Ecur[tail]
            float4 rl4 = *(const float4*)(Rel + rt * 64 + c4);
            float sc = q.x * kt.x * rl4.x + q.y * kt.y * rl4.y
                     + q.z * kt.z * rl4.z + q.w * kt.w * rl4.w;
            sc += __shfl_xor(sc, 1);       // reduce 8 lanes = one head, intra-slot
            sc += __shfl_xor(sc, 2);
            sc += __shfl_xor(sc, 4);
            float ex = __expf(sc * 0.17677669529663687f);  // 1/sqrt(32); scores tiny
            ex = act ? ex : 0.f;
            den += ex;
            acc.x += ex * te.x * rl4.x;
            acc.y += ex * te.y * rl4.y;
            acc.z += ex * te.z * rl4.z;
            acc.w += ex * te.w * rl4.w;
        }
        // cross-slot totals (each slot covered a disjoint edge subset)
        acc.x += __shfl_xor(acc.x, 16); acc.x += __shfl_xor(acc.x, 32);
        acc.y += __shfl_xor(acc.y, 16); acc.y += __shfl_xor(acc.y, 32);
        acc.z += __shfl_xor(acc.z, 16); acc.z += __shfl_xor(acc.z, 32);
        acc.w += __shfl_xor(acc.w, 16); acc.w += __shfl_xor(acc.w, 32);
        den   += __shfl_xor(den, 16);   den   += __shfl_xor(den, 32);
        float invd = (den > 0.f) ? 1.f / den : 0.f;   // deferred softmax division
        float4 val = make_float4(acc.x * invd, acc.y * invd, acc.z * invd, acc.w * invd);
        float ss = val.x * val.x + val.y * val.y + val.z * val.z + val.w * val.w;
        ss += __shfl_xor(ss, 1); ss += __shfl_xor(ss, 2);
        ss += __shfl_xor(ss, 4); ss += __shfl_xor(ss, 8);   // 16 g-lanes = all 64 ch
        float inv = 1.f / fmaxf(sqrtf(ss), 1e-12f);
        val.x *= inv; val.y *= inv; val.z *= inv; val.w *= inv;
        if (s == 0) {                       // one slot writes (all slots identical)
            *(float4*)(EQnext + (size_t)row * 128 + 64 + c4) = val;
            float4 r0 = *(const float4*)(Eres + (size_t)row * 64 + c4);
            r0.x += val.x; r0.y += val.y; r0.z += val.z; r0.w += val.w;
            *(float4*)(Eres + (size_t)row * 64 + c4) = r0;
        }
    } else {
        int row = wid - NEN;                // user node
        int beg = startU[row], end = beg + cntU[row];
        float4 acc = make_float4(0.f, 0.f, 0.f, 0.f);
        for (int j = beg; j < end; j += 4) {
            int jj = j + s;
            bool act = (jj < end);
            int idx = act ? jj : beg;
            int2 ew = *(const int2*)(csrU2 + 2 * (size_t)idx);
            float w = act ? __int_as_float(ew.y) : 0.f;
            float4 te = *(const float4*)(EQ + (size_t)ew.x * 128 + 64 + c4);
            acc.x += w * te.x; acc.y += w * te.y; acc.z += w * te.z; acc.w += w * te.w;
        }
        acc.x += __shfl_xor(acc.x, 16); acc.x += __shfl_xor(acc.x, 32);
        acc.y += __shfl_xor(acc.y, 16); acc.y += __shfl_xor(acc.y, 32);
        acc.z += __shfl_xor(acc.z, 16); acc.z += __shfl_xor(acc.z, 32);
        acc.w += __shfl_xor(acc.w, 16); acc.w += __shfl_xor(acc.w, 32);
        float ss = acc.x * acc.x + acc.y * acc.y + acc.z * acc.z + acc.w * acc.w;
        ss += __shfl_xor(ss, 1); ss += __shfl_xor(ss, 2);
        ss += __shfl_xor(ss, 4); ss += __shfl_xor(ss, 8);
        float inv = 1.f / fmaxf(sqrtf(ss), 1e-12f);
        if (s == 0) {
            float4 r0 = *(const float4*)(Ures + (size_t)row * 64 + c4);
            r0.x += acc.x * inv; r0.y += acc.y * inv;
            r0.z += acc.z * inv; r0.w += acc.w * inv;
            *(float4*)(Ures + (size_t)row * 64 + c4) = r0;
        }
    }
}

extern "C" void kernel_launch(void* const* d_in, const int* in_sizes, int n_in,
                              void* d_out, int out_size, void* d_ws, size_t ws_size,
                              hipStream_t stream)
{
    const float* ue = (const float*)d_in[0];
    const float* ee = (const float*)d_in[1];
    const float* re = (const float*)d_in[2];
    const float* wq = (const float*)d_in[3];
    const float* iw = (const float*)d_in[4];
    const int* eidx  = (const int*)d_in[5];
    const int* etype = (const int*)d_in[6];
    const int* ii    = (const int*)d_in[7];

    float* Eres = (float*)d_out;                 // residuals live in d_out directly
    float* Ures = Eres + (size_t)NEN * CH;

    // ws carve (~131 MB)
    float* EQ_A  = (float*)d_ws;                 // NEN*128
    float* EQ_B  = EQ_A + (size_t)NEN * 128;     // NEN*128
    float* Rel   = EQ_B + (size_t)NEN * 128;
    float* Wq    = Rel  + (size_t)NRELM1 * CH;
    int* cntE    = (int*)(Wq + (size_t)CH * CH);
    int* startE  = cntE    + NEN;
    int* curE    = startE  + NEN;
    int* cntU    = curE    + NEN;
    int* startU  = cntU    + NU;
    int* curU    = startU  + NU;
    int* cursors = curU    + NU;                 // 2 ints
    int* csrE    = cursors + 2;                  // NEDGE (even offset -> 8B align ok)
    int* csrU2   = csrE    + NEDGE;              // 2*NINTER

    const int nbE = (NEN + 255) >> 8, nbU = (NU + 255) >> 8;

    k_init<<<(NEN * CH) / 256, 256, 0, stream>>>(ue, ee, re, wq, EQ_A, Eres, Ures,
                                                 Rel, Wq, cntE, cntU, cursors);
    k_hist<<<(NEDGE + 255) / 256, 256, 0, stream>>>(eidx, ii, cntE, cntU);
    k_alloc<<<nbE + nbU, 256, 0, stream>>>(cntE, startE, curE, cntU, startU, curU, cursors);
    k_scatter<<<(NEDGE + 255) / 256, 256, 0, stream>>>(eidx, etype, ii, iw,
                                                       curE, csrE, curU,
                                                       (unsigned long long*)csrU2);

    float* EQc = EQ_A;
    float* EQn = EQ_B;
    for (int hop = 0; hop < 2; ++hop) {
        k_gemm <<<NEN / 4, 256, 0, stream>>>(EQc, Wq);
        k_fused<<<(NEN + NU) / 4, 256, 0, stream>>>(startE, cntE, csrE, EQc, Rel,
                                                    EQn, Eres, startU, cntU, csrU2, Ures);
        float* tmp = EQc; EQc = EQn; EQn = tmp;
    }
}

// Round 8
// 840.585 us; speedup vs baseline: 2.2690x; 1.0715x over previous
//
#include <hip/hip_runtime.h>

#define NU     50000
#define NEN    100000
#define NEDGE  2000000
#define NINTER 1000000
#define CH     64
#define NRELM1 9

typedef _Float16 hv2 __attribute__((ext_vector_type(2)));
union P4 { float4 f; hv2 h[4]; };   // 16B = 8 halves

// ---- init: inputs -> f16 working embeddings + f32 residuals, zero counters ----
__global__ __launch_bounds__(256) void k_init(
    const float* __restrict__ ue, const float* __restrict__ ee,
    const float* __restrict__ re, const float* __restrict__ wq,
    _Float16* __restrict__ Eh, float* __restrict__ Eres, float* __restrict__ Ures,
    _Float16* __restrict__ Relh, float* __restrict__ Wq,
    int* __restrict__ cntE, int* __restrict__ cntU, int* __restrict__ cursors)
{
    int i = blockIdx.x * 256 + threadIdx.x;           // grid covers NEN*CH
    if (i < NEN * CH) {
        float f = ee[i];
        Eh[i] = (_Float16)f;
        Eres[i] = f;
    }
    if (i < NU * CH)  Ures[i] = ue[i];
    if (i < NRELM1 * CH) Relh[i] = (_Float16)re[i];
    if (i < CH * CH)     Wq[i]  = wq[i];
    if (i < NEN) cntE[i] = 0;
    if (i < NU)  cntU[i] = 0;
    if (i < 2)   cursors[i] = 0;
}

// ---- degree histograms ----
__global__ __launch_bounds__(256) void k_hist(
    const int* __restrict__ eidx, const int* __restrict__ ii,
    int* __restrict__ cntE, int* __restrict__ cntU)
{
    int t = blockIdx.x * 256 + threadIdx.x;
    if (t < NEDGE) atomicAdd(&cntE[eidx[t]], 1);
    if (t < NINTER) atomicAdd(&cntU[ii[t]], 1);
}

// ---- CSR start allocation: unordered contiguous ranges via wave-aggregated atomics ----
__global__ __launch_bounds__(256) void k_alloc(
    const int* __restrict__ cntE, int* __restrict__ startE, int* __restrict__ curE,
    const int* __restrict__ cntU, int* __restrict__ startU, int* __restrict__ curU,
    int* __restrict__ cursors)
{
    const int nbE = (NEN + 255) >> 8;
    int b = blockIdx.x;
    const int* cnt; int* start; int* cur; int* cursor; int n; int node;
    if (b < nbE) { cnt = cntE; start = startE; cur = curE; cursor = cursors;     n = NEN;
                   node = b * 256 + threadIdx.x; }
    else         { cnt = cntU; start = startU; cur = curU; cursor = cursors + 1; n = NU;
                   node = (b - nbE) * 256 + threadIdx.x; }
    int c = (node < n) ? cnt[node] : 0;
    int lane = threadIdx.x & 63;
    int pre = c;                                // inclusive wave prefix sum
#pragma unroll
    for (int m = 1; m < 64; m <<= 1) {
        int v = __shfl_up(pre, m);
        if (lane >= m) pre += v;
    }
    int total = __shfl(pre, 63);
    int base = 0;
    if (lane == 63) base = atomicAdd(cursor, total);
    base = __shfl(base, 63);
    if (node < n) {
        int st = base + pre - c;                // exclusive within wave
        start[node] = st;
        cur[node]   = st;
    }
}

// ---- scatter edges into CSR slots (agent-scope/sc1 stores: merge in shared L3,
//      avoids per-XCD L2 partial-line write amplification) ----
__global__ __launch_bounds__(256) void k_scatter(
    const int* __restrict__ eidx, const int* __restrict__ etype,
    const int* __restrict__ ii, const float* __restrict__ iw,
    int* __restrict__ curE, int* __restrict__ csrE,
    int* __restrict__ curU, unsigned long long* __restrict__ csrU2)
{
    int t = blockIdx.x * 256 + threadIdx.x;
    if (t < NEDGE) {
        int head = eidx[t], tail = eidx[NEDGE + t], rt = etype[t] - 1;
        int pos = atomicAdd(&curE[head], 1);
        __hip_atomic_store(&csrE[pos], tail | (rt << 17),
                           __ATOMIC_RELAXED, __HIP_MEMORY_SCOPE_AGENT);
    }
    if (t < NINTER) {
        int u = ii[t], ent = ii[NINTER + t];
        int pos = atomicAdd(&curU[u], 1);
        unsigned long long rec = (unsigned long long)(unsigned)ent
                               | ((unsigned long long)__float_as_uint(iw[t]) << 32);
        __hip_atomic_store(&csrU2[pos], rec,
                           __ATOMIC_RELAXED, __HIP_MEMORY_SCOPE_AGENT);
    }
}

// ---- Qh = Eh @ W  (f16 in/out, f32 math; W in LDS; 4 rows/block) ----
__global__ __launch_bounds__(256) void k_gemm(
    const _Float16* __restrict__ Eh, float* __restrict__ Wq, _Float16* __restrict__ Qh)
{
    __shared__ float Wl[64 * 64];
    __shared__ float Rowl[4 * 64];
    int tid = threadIdx.x;
    for (int i = tid; i < 64 * 64; i += 256) Wl[i] = Wq[i];
    int row0 = blockIdx.x * 4;
    int rl = tid >> 6, c = tid & 63;
    Rowl[tid] = (float)Eh[(row0 + rl) * 64 + c];
    __syncthreads();
    float acc = 0.f;
#pragma unroll
    for (int k = 0; k < 64; ++k) acc += Rowl[rl * 64 + k] * Wl[k * 64 + c];
    Qh[(row0 + rl) * 64 + c] = (_Float16)acc;
}

// ---- fused per-node pass: entities (attention) + users (weighted mean) ----
// one wave per node; 8 edge-slots x 8 lanes; 8 halves (16B) per lane
__global__ __launch_bounds__(256) void k_fused(
    const int* __restrict__ startE, const int* __restrict__ cntE,
    const int* __restrict__ csrE,
    const _Float16* __restrict__ Qh, const _Float16* __restrict__ Eh,
    const _Float16* __restrict__ Relh,
    _Float16* __restrict__ Ehn, float* __restrict__ Eres,
    const int* __restrict__ startU, const int* __restrict__ cntU,
    const unsigned long long* __restrict__ csrU2, float* __restrict__ Ures)
{
    int wid  = blockIdx.x * 4 + (threadIdx.x >> 6);
    int lane = threadIdx.x & 63;
    int s = lane >> 3, l = lane & 7;            // slot, lane-in-slot
    int c8 = l * 8;                             // this lane's 8 channels

    if (wid < NEN) {
        int row = wid;
        int beg = startE[row], end = beg + cntE[row];
        P4 q; q.f = *(const float4*)(Qh + (size_t)row * 64 + c8);
        float qf[8];
#pragma unroll
        for (int i = 0; i < 4; ++i) { qf[2*i] = (float)q.h[i].x; qf[2*i+1] = (float)q.h[i].y; }
        float acc[8] = {0.f,0.f,0.f,0.f,0.f,0.f,0.f,0.f};
        float den = 0.f;
        for (int j = beg; j < end; j += 8) {
            int jj = j + s;
            bool act = (jj < end);
            int p = csrE[act ? jj : beg];
            int tail = p & 0x1FFFF;
            int rt   = p >> 17;
            P4 kt, te, rl;
            kt.f = *(const float4*)(Qh   + (size_t)tail * 64 + c8);
            te.f = *(const float4*)(Eh   + (size_t)tail * 64 + c8);
            rl.f = *(const float4*)(Relh + rt * 64 + c8);
            float sc = 0.f;
#pragma unroll
            for (int i = 0; i < 4; ++i) {
                hv2 km = kt.h[i] * rl.h[i];     // v_pk_mul_f16
                sc += qf[2*i] * (float)km.x + qf[2*i+1] * (float)km.y;
            }
            // reduce over the 4 lanes holding this head's channels (l^1, l^2)
            sc += __shfl_xor(sc, 1);
            sc += __shfl_xor(sc, 2);
            float ex = __expf(sc * 0.17677669529663687f);  // 1/sqrt(32); scores tiny
            ex = act ? ex : 0.f;
            den += ex;
#pragma unroll
            for (int i = 0; i < 4; ++i) {
                hv2 vm = te.h[i] * rl.h[i];
                acc[2*i]   += ex * (float)vm.x;
                acc[2*i+1] += ex * (float)vm.y;
            }
        }
        // cross-slot totals (slots covered disjoint edge subsets)
#pragma unroll
        for (int k = 0; k < 8; ++k) {
            acc[k] += __shfl_xor(acc[k], 8);
            acc[k] += __shfl_xor(acc[k], 16);
            acc[k] += __shfl_xor(acc[k], 32);
        }
        den += __shfl_xor(den, 8); den += __shfl_xor(den, 16); den += __shfl_xor(den, 32);
        float invd = (den > 0.f) ? 1.f / den : 0.f;   // deferred softmax division
        float ss = 0.f;
#pragma unroll
        for (int k = 0; k < 8; ++k) { acc[k] *= invd; ss += acc[k] * acc[k]; }
        ss += __shfl_xor(ss, 1); ss += __shfl_xor(ss, 2); ss += __shfl_xor(ss, 4);
        float inv = 1.f / fmaxf(sqrtf(ss), 1e-12f);
#pragma unroll
        for (int k = 0; k < 8; ++k) acc[k] *= inv;
        if (s == 0) {                           // one slot writes
            P4 o;
#pragma unroll
            for (int i = 0; i < 4; ++i) { o.h[i].x = (_Float16)acc[2*i]; o.h[i].y = (_Float16)acc[2*i+1]; }
            *(float4*)(Ehn + (size_t)row * 64 + c8) = o.f;
            float4 r0 = *(const float4*)(Eres + (size_t)row * 64 + c8);
            float4 r1 = *(const float4*)(Eres + (size_t)row * 64 + c8 + 4);
            r0.x += acc[0]; r0.y += acc[1]; r0.z += acc[2]; r0.w += acc[3];
            r1.x += acc[4]; r1.y += acc[5]; r1.z += acc[6]; r1.w += acc[7];
            *(float4*)(Eres + (size_t)row * 64 + c8)     = r0;
            *(float4*)(Eres + (size_t)row * 64 + c8 + 4) = r1;
        }
    } else {
        int row = wid - NEN;                    // user node
        int beg = startU[row], end = beg + cntU[row];
        float acc[8] = {0.f,0.f,0.f,0.f,0.f,0.f,0.f,0.f};
        for (int j = beg; j < end; j += 8) {
            int jj = j + s;
            bool act = (jj < end);
            unsigned long long rec = csrU2[act ? jj : beg];
            int ent = (int)(unsigned)rec;
            float w = act ? __uint_as_float((unsigned)(rec >> 32)) : 0.f;
            P4 te; te.f = *(const float4*)(Eh + (size_t)ent * 64 + c8);
#pragma unroll
            for (int i = 0; i < 4; ++i) {
                acc[2*i]   += w * (float)te.h[i].x;
                acc[2*i+1] += w * (float)te.h[i].y;
            }
        }
#pragma unroll
        for (int k = 0; k < 8; ++k) {
            acc[k] += __shfl_xor(acc[k], 8);
            acc[k] += __shfl_xor(acc[k], 16);
            acc[k] += __shfl_xor(acc[k], 32);
        }
        float ss = 0.f;
#pragma unroll
        for (int k = 0; k < 8; ++k) ss += acc[k] * acc[k];
        ss += __shfl_xor(ss, 1); ss += __shfl_xor(ss, 2); ss += __shfl_xor(ss, 4);
        float inv = 1.f / fmaxf(sqrtf(ss), 1e-12f);
        if (s == 0) {
            float4 r0 = *(const float4*)(Ures + (size_t)row * 64 + c8);
            float4 r1 = *(const float4*)(Ures + (size_t)row * 64 + c8 + 4);
            r0.x += acc[0] * inv; r0.y += acc[1] * inv; r0.z += acc[2] * inv; r0.w += acc[3] * inv;
            r1.x += acc[4] * inv; r1.y += acc[5] * inv; r1.z += acc[6] * inv; r1.w += acc[7] * inv;
            *(float4*)(Ures + (size_t)row * 64 + c8)     = r0;
            *(float4*)(Ures + (size_t)row * 64 + c8 + 4) = r1;
        }
    }
}

extern "C" void kernel_launch(void* const* d_in, const int* in_sizes, int n_in,
                              void* d_out, int out_size, void* d_ws, size_t ws_size,
                              hipStream_t stream)
{
    const float* ue = (const float*)d_in[0];
    const float* ee = (const float*)d_in[1];
    const float* re = (const float*)d_in[2];
    const float* wq = (const float*)d_in[3];
    const float* iw = (const float*)d_in[4];
    const int* eidx  = (const int*)d_in[5];
    const int* etype = (const int*)d_in[6];
    const int* ii    = (const int*)d_in[7];

    float* Eres = (float*)d_out;                 // residuals live in d_out directly
    float* Ures = Eres + (size_t)NEN * CH;

    // ws carve: f32 W, int CSR region, then 16B-aligned f16 embeddings (~56 MB)
    float* Wq    = (float*)d_ws;                          // 4096 f32
    int* cntE    = (int*)(Wq + 4096);
    int* startE  = cntE    + NEN;
    int* curE    = startE  + NEN;
    int* cntU    = curE    + NEN;
    int* startU  = cntU    + NU;
    int* curU    = startU  + NU;
    int* cursors = curU    + NU;                          // 2 ints (8B-aligned here)
    unsigned long long* csrU2 = (unsigned long long*)(cursors + 2);  // NINTER x 8B
    int* csrE    = (int*)(csrU2 + NINTER);                // NEDGE ints
    int* pad     = csrE + NEDGE;                          // +2 ints -> 16B align
    _Float16* Qh   = (_Float16*)(pad + 2);                // NEN*64 halves
    _Float16* EhA  = Qh  + (size_t)NEN * CH;
    _Float16* EhB  = EhA + (size_t)NEN * CH;
    _Float16* Relh = EhB + (size_t)NEN * CH;              // 9*64 halves

    const int nbE = (NEN + 255) >> 8, nbU = (NU + 255) >> 8;

    k_init<<<(NEN * CH) / 256, 256, 0, stream>>>(ue, ee, re, wq, EhA, Eres, Ures,
                                                 Relh, Wq, cntE, cntU, cursors);
    k_hist<<<(NEDGE + 255) / 256, 256, 0, stream>>>(eidx, ii, cntE, cntU);
    k_alloc<<<nbE + nbU, 256, 0, stream>>>(cntE, startE, curE, cntU, startU, curU, cursors);
    k_scatter<<<(NEDGE + 255) / 256, 256, 0, stream>>>(eidx, etype, ii, iw,
                                                       curE, csrE, curU, csrU2);

    _Float16* Ehc = EhA;
    _Float16* Ehn = EhB;
    for (int hop = 0; hop < 2; ++hop) {
        k_gemm <<<NEN / 4, 256, 0, stream>>>(Ehc, Wq, Qh);
        k_fused<<<(NEN + NU) / 4, 256, 0, stream>>>(startE, cntE, csrE, Qh, Ehc, Relh,
                                                    Ehn, Eres, startU, cntU, csrU2, Ures);
        _Float16* tmp = Ehc; Ehc = Ehn; Ehn = tmp;
    }
}